// Round 5
// baseline (772.608 us; speedup 1.0000x reference)
//
#include <hip/hip_runtime.h>

// OLSTM: T=20 frames, N=50000 nodes, K=10000 active peds/frame
// RNN=128, EMB=64, IN=2, OUT=5, G2=16
//
// Round 12: occupancy via 16-wave blocks (same 511 blocks, same fixed costs --
// the round-8 trap was SPLITTING blocks, not occupancy itself). 1024 thr =
// 4 waves/SIMD (50% occ, was 25%). Register budget 128/wave forces B-split:
// wave w holds 32 GEMM cols (Breg[2][8]=64 regs: n-tile0 = gates{i,f}, tile1 =
// {g,o} for units 8w..8w+8); lane pairs (cl, cl^8) reassemble 4 gates via
// shfl_xor(8), 2 peds/lane. Wave-role split, 2 barriers/frame:
//   A: w0-7 build uS | w8-15 out-proj(t-1) + issue gathers(t+1)
//   B: all GEMM+LSTM; w8-15 commit gX + zero-fill(t)
// Winner resolution folded into olstm prologue (16 waves x 20 frames,
// LDS-local) -> no winner_kernel, no per-frame list prefetch. 3 dispatches.
#define TT    20
#define NN    50000
#define KK    10000
#define RNN   128
#define EMB   64
#define GG2   16
#define NOUT  5
#define NODEB 98
#define NBLK  ((NN + NODEB - 1) / NODEB)   // 511 blocks
#define CAP   64                           // peds per (frame, block); E[n]=19.6
#define NTHR  1024                         // 16 waves

// LDS-only barrier: orders ds ops across waves without draining vmcnt.
// Matters now: gathers issued in A are committed in B (one phase later).
#define BAR_LDS() do { \
    __builtin_amdgcn_sched_barrier(0); \
    asm volatile("s_waitcnt lgkmcnt(0)" ::: "memory"); \
    __builtin_amdgcn_s_barrier(); \
    __builtin_amdgcn_sched_barrier(0); \
} while (0)

typedef __attribute__((ext_vector_type(8))) short bf16x8;
typedef __attribute__((ext_vector_type(4))) float f32x4;

__device__ __forceinline__ unsigned short f2b(float x) {  // fp32 -> bf16, RNE
    union { float f; unsigned u; } v; v.f = x;
    return (unsigned short)((v.u + 0x7FFF + ((v.u >> 16) & 1)) >> 16);
}
__device__ __forceinline__ unsigned pack2(float a, float b) {
    return (unsigned)f2b(a) | ((unsigned)f2b(b) << 16);
}
__device__ __forceinline__ float sigf(float x)   { return 1.f / (1.f + __expf(-x)); }
__device__ __forceinline__ float tanh_f(float x) { return 2.f / (1.f + __expf(-2.f * x)) - 1.f; }

struct Params {
    const float* input_data; const float* grids;
    const float* h0; const float* c0;
    const float* W_in;  const float* b_in;
    const float* W_obs; const float* b_obs;
    const float* b_out;
    float* outputs; float* h_all; float* c_all;
    const unsigned short* Wt; const float* biasp; const float* W_outT;
    const int* cnt; const int* lists;
};

struct SmemT {
    float hS[NODEB][132];          // owned h state, fp32 (pad 132: bank spread)
    float cS[NODEB][132];          // owned c state, fp32
    unsigned short uS[32][264];    // GEMM A: [ie(64) te(64) h(128)] bf16;
                                   // prologue: aliased as 16x98 int wslot scratch
    float gX[2][CAP][20];          // double-buffered per-winner grid(16)+x(2)
    float wObs[GG2][EMB];          // small weights, LDS-resident
    float wIn[2][EMB];
    float bIn[EMB];
    float bObs[EMB];
    float wOutT[NOUT][132];        // pad 132: breaks 5-way bank conflict
    float bOut[8];
    int wLall[TT][CAP];            // ALL winner lists (resolved in prologue)
    unsigned wMask[TT][4];         // winner-node bitmasks (zero-fill disjointness)
    int wCnt[TT];
};                                 // ~140.6 KB of 160 KB -> 1 block/CU

// Weight prep, coalesced via LDS tile transpose. New 16-wave permute:
// cp = 32*wv + 16*tile + cl -> orig col = 128*(2*tile + (cl>>3)) + 8*wv + (cl&7)
// (wave wv n-tile0 = gates{i,f}, tile1 = {g,o}, units 8wv..8wv+8).
__global__ __launch_bounds__(256) void prep_kernel(
    const float* __restrict__ Wih, const float* __restrict__ Whh,
    const float* __restrict__ bih, const float* __restrict__ bhh,
    const float* __restrict__ Wout,
    unsigned short* __restrict__ Wt, float* __restrict__ biasp,
    float* __restrict__ WoutT, int* __restrict__ cnt)
{
    __shared__ float tile[16][513];
    const int bx = blockIdx.x, tid = threadIdx.x;
    const int k0 = bx * 16;
    for (int i = tid; i < 16 * 512; i += 256) {
        int rr = i >> 9, cc = i & 511;
        int k = k0 + rr;
        tile[rr][cc] = (k < 128) ? Wih[k * 512 + cc] : Whh[(k - 128) * 512 + cc];
    }
    __syncthreads();
    for (int i = tid; i < 1024; i += 256) {      // 512 cp x 2 chunks of 8 k
        int cp = i >> 1, ch = i & 1;
        int wv = cp >> 5, tl = (cp >> 4) & 1, cl2 = cp & 15;
        int oc = 128 * (2 * tl + (cl2 >> 3)) + 8 * wv + (cl2 & 7);
        union { bf16x8 v; unsigned short s[8]; } u;
        #pragma unroll
        for (int e = 0; e < 8; ++e) u.s[e] = f2b(tile[8 * ch + e][oc]);
        *(bf16x8*)&Wt[cp * 256 + k0 + 8 * ch] = u.v;
    }
    if (bx == 0) {
        for (int cp = tid; cp < 512; cp += 256) {
            int wv = cp >> 5, tl = (cp >> 4) & 1, cl2 = cp & 15;
            int oc = 128 * (2 * tl + (cl2 >> 3)) + 8 * wv + (cl2 & 7);
            biasp[cp] = bih[oc] + bhh[oc];
        }
        for (int e = tid; e < NOUT * RNN; e += 256)
            WoutT[e] = Wout[(e & 127) * NOUT + (e >> 7)];
    }
    for (int i = bx * 256 + tid; i < TT * NBLK; i += 16 * 256) cnt[i] = 0;
}

// Bin each (t,k) ped to its node-owner block. Entry = k | (node_local << 14).
__global__ __launch_bounds__(256) void bin_kernel(
    const int* __restrict__ idx, int* __restrict__ cnt, int* __restrict__ lists)
{
    int e = blockIdx.x * 256 + threadIdx.x;
    if (e >= TT * KK) return;
    int t = e / KK, k = e - t * KK;
    int nd = idx[e];
    int ow = nd / NODEB, nl = nd - ow * NODEB;
    int slot = atomicAdd(&cnt[t * NBLK + ow], 1);
    if (slot < CAP) lists[((size_t)(t * NBLK + ow)) * CAP + slot] = k | (nl << 14);
}

__global__ __launch_bounds__(NTHR, 4) void olstm_kernel(Params P) {
    extern __shared__ char smem_raw[];
    SmemT& S = *(SmemT*)smem_raw;
    const int tid = threadIdx.x;
    const int b   = blockIdx.x;
    const int n0  = b * NODEB;
    const int nown = (NN - n0 < NODEB) ? (NN - n0) : NODEB;
    const int w = tid >> 6, lane = tid & 63;
    const int cl = lane & 15, kq = lane >> 4;
    const int tidp = tid - 512;                   // aux-thread index (w8-15)
    const int d5 = tidp / 5, r5 = tidp - 5 * d5;  // used only when tid>=512
    const int zw = d5 >> 5, zb = d5 & 31;

    // ---- prologue: state (float4) + small weights -> LDS ----
    for (int i4 = tid * 4; i4 < nown * RNN; i4 += NTHR * 4) {
        int nl = i4 >> 7, r = i4 & 127;
        *(float4*)&S.hS[nl][r] = *(const float4*)(P.h0 + (size_t)n0 * RNN + i4);
        *(float4*)&S.cS[nl][r] = *(const float4*)(P.c0 + (size_t)n0 * RNN + i4);
    }
    for (int i = tid; i < GG2 * EMB; i += NTHR) S.wObs[i >> 6][i & 63] = P.W_obs[i];
    if (tid < 2 * EMB) S.wIn[tid >> 6][tid & 63] = P.W_in[tid];
    if (tid < EMB) { S.bIn[tid] = P.b_in[tid]; S.bObs[tid] = P.b_obs[tid]; }
    for (int i = tid; i < NOUT * RNN; i += NTHR) S.wOutT[i >> 7][i & 127] = P.W_outT[i];
    if (tid < NOUT) S.bOut[tid] = P.b_out[tid];

    // ---- B-stationary slice: 32 cols/wave -> 64 regs + 2 bias regs ----
    bf16x8 Breg[2][8];
    float bv[2];
    #pragma unroll
    for (int tl = 0; tl < 2; ++tl) {
        const unsigned short* Wb = P.Wt + ((size_t)(32 * w + 16 * tl + cl)) * 256 + kq * 8;
        #pragma unroll
        for (int ks = 0; ks < 8; ++ks) Breg[tl][ks] = *(const bf16x8*)(Wb + ks * 32);
        bv[tl] = P.biasp[32 * w + 16 * tl + cl];
    }

    // ---- winner resolution, all 20 frames (wave w: frames w, w+16);
    //      wslot scratch aliased into uS; single-wave in-order DS ----
    {
        int* wslBase = (int*)&S.uS[0][0];
        for (int t = w; t < TT; t += 16) {
            const int g = t * NBLK + b;
            int c = P.cnt[g]; c = (c > CAP) ? CAP : c;
            int* wsl = wslBase + w * NODEB;
            wsl[lane] = -1;
            if (lane + 64 < NODEB) wsl[lane + 64] = -1;
            if (lane < 4) S.wMask[t][lane] = 0u;
            int ent = 0, mk = -1, mnl = 0;
            if (lane < c) {
                ent = P.lists[(size_t)g * CAP + lane];
                mnl = ent >> 14; mk = ent & 0x3FFF;
                atomicMax(&wsl[mnl], mk);
            }
            const bool win = (lane < c) && (wsl[mnl] == mk);
            const unsigned long long ball = __ballot(win);
            const int slot = __popcll(ball & ((1ull << lane) - 1ull));
            if (win) {
                S.wLall[t][slot] = ent;
                atomicOr(&S.wMask[t][mnl >> 5], 1u << (mnl & 31));
            }
            if (lane == 0) S.wCnt[t] = __popcll(ball);
        }
    }
    BAR_LDS();

    // ---- stage gX[0] (only frame whose gather latency is exposed) ----
    if (tid >= 512) {
        const int wn0 = S.wCnt[0];
        if (tidp < 256) {
            int gm0 = tidp >> 2;
            if (gm0 < wn0) {
                int kk2 = S.wLall[0][gm0] & 0x3FFF;
                float4 gv0 = *(const float4*)(P.grids + (size_t)kk2 * GG2 + (tidp & 3) * 4);
                *(float4*)&S.gX[0][gm0][(tidp & 3) * 4] = gv0;
            }
        } else if (tidp < 320) {
            int xm = tidp - 256;
            if (xm < wn0) {
                int nl = S.wLall[0][xm] >> 14;
                float2 x2 = *(const float2*)(P.input_data + ((size_t)(n0 + nl)) * 2);
                S.gX[0][xm][16] = x2.x; S.gX[0][xm][17] = x2.y;
            }
        }
    }
    BAR_LDS();

    // ---- uS build for one 32-row super-tile (threads 0..511) ----
    auto build_tile = [&](int tf, int base, int msx) {
        const int m = tid >> 4, l = tid & 15;
        const int mrows = ((msx > 16) ? 2 : 1) << 4;
        if (m >= mrows) return;
        if (m < msx) {
            const int e = S.wLall[tf][base + m];
            const int nl2 = e >> 14;
            const float4 ha = *(const float4*)&S.hS[nl2][l * 4];
            const float4 hb = *(const float4*)&S.hS[nl2][64 + l * 4];
            *(uint2*)&S.uS[m][128 + l * 4] = make_uint2(pack2(ha.x, ha.y), pack2(ha.z, ha.w));
            *(uint2*)&S.uS[m][192 + l * 4] = make_uint2(pack2(hb.x, hb.y), pack2(hb.z, hb.w));
            const float* gx = S.gX[tf & 1][base + m];
            const float x0 = gx[16], x1 = gx[17];
            const int e0 = l * 4;
            float iv[4], tv[4];
            #pragma unroll
            for (int j = 0; j < 4; ++j) {
                iv[j] = fmaxf(fmaf(x0, S.wIn[0][e0 + j],
                              fmaf(x1, S.wIn[1][e0 + j], S.bIn[e0 + j])), 0.f);
                tv[j] = S.bObs[e0 + j];
            }
            #pragma unroll
            for (int g = 0; g < GG2; ++g) {
                const float gg = gx[g];
                #pragma unroll
                for (int j = 0; j < 4; ++j)
                    tv[j] = fmaf(gg, S.wObs[g][e0 + j], tv[j]);
            }
            *(uint2*)&S.uS[m][l * 4] =
                make_uint2(pack2(iv[0], iv[1]), pack2(iv[2], iv[3]));
            *(uint2*)&S.uS[m][64 + l * 4] =
                make_uint2(pack2(fmaxf(tv[0], 0.f), fmaxf(tv[1], 0.f)),
                           pack2(fmaxf(tv[2], 0.f), fmaxf(tv[3], 0.f)));
        } else {
            const uint2 z2 = make_uint2(0u, 0u);
            *(uint2*)&S.uS[m][l * 4]       = z2;
            *(uint2*)&S.uS[m][64 + l * 4]  = z2;
            *(uint2*)&S.uS[m][128 + l * 4] = z2;
            *(uint2*)&S.uS[m][192 + l * 4] = z2;
        }
    };

    // ---- LSTM for one 16-row m-tile: lane pair (cl, cl^8) swaps gate halves,
    //      each lane finishes 2 peds. tile0 = {i,f}, tile1 = {g,o}. ----
    const bool lolane = (cl < 8);
    const int u = 8 * w + (cl & 7);
    auto lstm_half = [&](const f32x4* ac, int mtb, int tf, int base, int msx) {
        const float r00 = __shfl_xor(ac[0][0], 8), r01 = __shfl_xor(ac[0][1], 8);
        const float r02 = __shfl_xor(ac[0][2], 8), r03 = __shfl_xor(ac[0][3], 8);
        const float r10 = __shfl_xor(ac[1][0], 8), r11 = __shfl_xor(ac[1][1], 8);
        const float r12 = __shfl_xor(ac[1][2], 8), r13 = __shfl_xor(ac[1][3], 8);
        #pragma unroll
        for (int jj = 0; jj < 2; ++jj) {
            const float a0lo = jj ? ac[0][1] : ac[0][0];
            const float a0hi = jj ? ac[0][3] : ac[0][2];
            const float a1lo = jj ? ac[1][1] : ac[1][0];
            const float a1hi = jj ? ac[1][3] : ac[1][2];
            const float r0lo = jj ? r01 : r00, r0hi = jj ? r03 : r02;
            const float r1lo = jj ? r11 : r10, r1hi = jj ? r13 : r12;
            const float iv = lolane ? a0lo : r0hi;
            const float fv = lolane ? r0lo : a0hi;
            const float gg = lolane ? a1lo : r1hi;
            const float ov = lolane ? r1lo : a1hi;
            const int m = mtb + 4 * kq + (lolane ? jj : jj + 2);
            if (m < msx) {
                const int nl2 = S.wLall[tf][base + m] >> 14;
                const float cn2 = fmaf(sigf(fv), S.cS[nl2][u], sigf(iv) * tanh_f(gg));
                const float hv = sigf(ov) * tanh_f(cn2);
                S.hS[nl2][u] = hv;   // exclusive (node, unit) per lane
                S.cS[nl2][u] = cn2;
            }
        }
    };

    auto gemm_lstm = [&](int tf, int base, int msx, int nmtx) {
        f32x4 acc0[2], acc1[2];
        #pragma unroll
        for (int tl = 0; tl < 2; ++tl) {
            acc0[tl] = (f32x4){bv[tl], bv[tl], bv[tl], bv[tl]};
            acc1[tl] = acc0[tl];
        }
        if (nmtx == 2) {
            #pragma unroll
            for (int ks = 0; ks < 8; ++ks) {
                const int kk = ks * 32;
                const bf16x8 a0 = *(const bf16x8*)&S.uS[cl][kk + kq * 8];
                const bf16x8 a1 = *(const bf16x8*)&S.uS[16 + cl][kk + kq * 8];
                #pragma unroll
                for (int tl = 0; tl < 2; ++tl) {
                    acc0[tl] = __builtin_amdgcn_mfma_f32_16x16x32_bf16(a0, Breg[tl][ks], acc0[tl], 0, 0, 0);
                    acc1[tl] = __builtin_amdgcn_mfma_f32_16x16x32_bf16(a1, Breg[tl][ks], acc1[tl], 0, 0, 0);
                }
            }
        } else {
            #pragma unroll
            for (int ks = 0; ks < 8; ++ks) {
                const int kk = ks * 32;
                const bf16x8 a0 = *(const bf16x8*)&S.uS[cl][kk + kq * 8];
                #pragma unroll
                for (int tl = 0; tl < 2; ++tl)
                    acc0[tl] = __builtin_amdgcn_mfma_f32_16x16x32_bf16(a0, Breg[tl][ks], acc0[tl], 0, 0, 0);
            }
        }
        lstm_half(acc0, 0, tf, base, msx);
        if (nmtx == 2) lstm_half(acc1, 16, tf, base, msx);
    };

    auto outproj = [&](int tf) {   // tid>=512 only; covers all wn(tf) winners
        const int wnp = S.wCnt[tf];
        if (tidp < wnp * NOUT) {
            const int nl2 = S.wLall[tf][d5] >> 14;
            const float* hp = S.hS[nl2];
            const float* wp = S.wOutT[r5];
            float a0 = S.bOut[r5], a1 = 0.f, a2 = 0.f, a3 = 0.f;
            #pragma unroll 8
            for (int rr = 0; rr < RNN; rr += 4) {
                const float4 h4 = *(const float4*)&hp[rr];
                const float4 w4 = *(const float4*)&wp[rr];
                a0 = fmaf(h4.x, w4.x, a0); a1 = fmaf(h4.y, w4.y, a1);
                a2 = fmaf(h4.z, w4.z, a2); a3 = fmaf(h4.w, w4.w, a3);
            }
            P.outputs[((size_t)tf * NN + n0 + nl2) * NOUT + r5] = (a0 + a1) + (a2 + a3);
        }
    };

    // ================= frame loop: 2 barriers/frame =================
    for (int t = 0; t < TT; ++t) {
        const int bufc = t & 1;
        const int wn = S.wCnt[t];
        const int ms0 = (wn < 32) ? wn : 32;
        const int nmt0 = (ms0 > 16) ? 2 : 1;

        float2 xv = {0.f, 0.f};
        float4 gv = {0.f, 0.f, 0.f, 0.f};
        int gm = 0, nwn = 0;

        // ---- Phase A: build(w0-7) || gather-issue(t+1) + out-proj(t-1) (w8-15)
        if (tid < 512) {
            build_tile(t, 0, ms0);
        } else {
            if (t + 1 < TT) {
                nwn = S.wCnt[t + 1];
                if (tidp < 256) {
                    gm = tidp >> 2;
                    if (gm < nwn) {
                        int kk2 = S.wLall[t + 1][gm] & 0x3FFF;
                        gv = *(const float4*)(P.grids + ((size_t)(t + 1) * KK + kk2) * GG2 + (tidp & 3) * 4);
                    }
                } else if (tidp < 320) {
                    int xm = tidp - 256;
                    if (xm < nwn) {
                        int nl = S.wLall[t + 1][xm] >> 14;
                        xv = *(const float2*)(P.input_data + ((size_t)(t + 1) * NN + n0 + nl) * 2);
                    }
                }
            }
            if (t > 0) outproj(t - 1);   // reads h(t-1); LSTM writes after BAR
        }
        BAR_LDS();

        // ---- Phase B: GEMM + LSTM (all 16 waves) ----
        gemm_lstm(t, 0, ms0, nmt0);
        for (int base = 32; base < wn; base += 32) {   // rare (P ~ 0.3%)
            BAR_LDS();
            if (tid < 512) {
                const int msx = (wn - base < 32) ? (wn - base) : 32;
                build_tile(t, base, msx);
            }
            BAR_LDS();
            const int msx = (wn - base < 32) ? (wn - base) : 32;
            gemm_lstm(t, base, msx, (msx > 16) ? 2 : 1);
        }
        // aux: commit gathers (issued one phase ago) + zero-fill non-winners
        if (tid >= 512) {
            if (t + 1 < TT) {
                if (tidp < 256) {
                    if (gm < nwn) *(float4*)&S.gX[bufc ^ 1][gm][(tidp & 3) * 4] = gv;
                } else if (tidp < 320) {
                    int xm = tidp - 256;
                    if (xm < nwn) { S.gX[bufc ^ 1][xm][16] = xv.x; S.gX[bufc ^ 1][xm][17] = xv.y; }
                }
            }
            if (tidp < nown * NOUT && !((S.wMask[t][zw] >> zb) & 1u))
                P.outputs[(size_t)t * NN * NOUT + n0 * NOUT + tidp] = 0.f;
        }
        BAR_LDS();
    }

    // ---- epilogue: out-proj(19) (w8-15) || state writeback (w0-7) ----
    if (tid >= 512) {
        outproj(TT - 1);
    } else {
        for (int i4 = tid * 4; i4 < nown * RNN; i4 += 512 * 4) {
            int nl = i4 >> 7, r = i4 & 127;
            *(float4*)(P.h_all + (size_t)n0 * RNN + i4) = *(const float4*)&S.hS[nl][r];
            *(float4*)(P.c_all + (size_t)n0 * RNN + i4) = *(const float4*)&S.cS[nl][r];
        }
    }
}

extern "C" void kernel_launch(void* const* d_in, const int* in_sizes, int n_in,
                              void* d_out, int out_size, void* d_ws, size_t ws_size,
                              hipStream_t stream) {
    Params P;
    P.input_data = (const float*)d_in[0];
    P.grids      = (const float*)d_in[1];
    P.h0         = (const float*)d_in[2];
    P.c0         = (const float*)d_in[3];
    const int* active_idx = (const int*)d_in[4];
    P.W_in  = (const float*)d_in[5];
    P.b_in  = (const float*)d_in[6];
    P.W_obs = (const float*)d_in[7];
    P.b_obs = (const float*)d_in[8];
    const float* W_ih = (const float*)d_in[9];
    const float* b_ih = (const float*)d_in[10];
    const float* W_hh = (const float*)d_in[11];
    const float* b_hh = (const float*)d_in[12];
    const float* W_out = (const float*)d_in[13];
    P.b_out = (const float*)d_in[14];

    // d_out: outputs[T*N*5] | h_fin[N*128] | c_fin[N*128]
    P.outputs = (float*)d_out;
    P.h_all   = P.outputs + (size_t)TT * NN * NOUT;
    P.c_all   = P.h_all + (size_t)NN * RNN;

    // d_ws: Wt | biasp | W_outT | cnt | lists
    char* ws = (char*)d_ws;
    unsigned short* Wt = (unsigned short*)ws;  ws += (size_t)512 * 256 * sizeof(unsigned short);
    float* biasp = (float*)ws;                 ws += 512 * sizeof(float);
    float* WoT   = (float*)ws;                 ws += (size_t)NOUT * RNN * sizeof(float);
    int* cnt     = (int*)ws;                   ws += (size_t)TT * NBLK * sizeof(int);
    int* lists   = (int*)ws;
    P.Wt = Wt; P.biasp = biasp; P.W_outT = WoT; P.cnt = cnt; P.lists = lists;

    // 3 dispatches (winner resolution folded into olstm prologue)
    prep_kernel<<<16, 256, 0, stream>>>(W_ih, W_hh, b_ih, b_hh, W_out, Wt, biasp, WoT, cnt);
    bin_kernel<<<(TT * KK + 255) / 256, 256, 0, stream>>>(active_idx, cnt, lists);

    // ~140.6 KB dynamic LDS (gfx950: 160 KB/CU) -> 1 block/CU, 16 waves (4/SIMD)
    int smem = (int)sizeof(SmemT);
    hipFuncSetAttribute((const void*)olstm_kernel,
                        hipFuncAttributeMaxDynamicSharedMemorySize, smem);
    olstm_kernel<<<NBLK, NTHR, smem, stream>>>(P);
}

// Round 6
// 708.495 us; speedup vs baseline: 1.0905x; 1.0905x over previous
//
#include <hip/hip_runtime.h>

// OLSTM: T=20 frames, N=50000 nodes, K=10000 active peds/frame
// RNN=128, EMB=64, IN=2, OUT=5, G2=16
//
// Round 13: round-12 16-wave structure with the register allocator PINNED.
// Round-12's 651us regression was pure regalloc sabotage: __launch_bounds__
// (1024,4) sets only a MIN waves/EU -> compiler went occupancy-greedy
// (8 waves/EU, 64 VGPR) and spilled Breg to scratch (WRITE_SIZE 527 MB).
// Fix: amdgpu_waves_per_eu(4,4) pins min=max=4 -> full 128-reg budget.
// Register relief: GEMM m-tiles sequential (acc working set halved).
// Structure (verified correct in r12): 511 blocks x 1024 thr (16 waves,
// 4/SIMD); wave w holds 32 GEMM cols (Breg[2][8]=64 regs; tile0={i,f},
// tile1={g,o}, units 8w..8w+8); lane pairs (cl, cl^8) swap gate halves via
// shfl_xor(8). 2 barriers/frame:
//   A: w0-7 build uS | w8-15 out-proj(t-1) + issue gathers(t+1)
//   B: all GEMM+LSTM; w8-15 commit gX + zero-fill(t)
// Winner resolution in olstm prologue; 3 dispatches.
#define TT    20
#define NN    50000
#define KK    10000
#define RNN   128
#define EMB   64
#define GG2   16
#define NOUT  5
#define NODEB 98
#define NBLK  ((NN + NODEB - 1) / NODEB)   // 511 blocks
#define CAP   64                           // peds per (frame, block); E[n]=19.6
#define NTHR  1024                         // 16 waves

// LDS-only barrier: orders ds ops across waves without draining vmcnt.
#define BAR_LDS() do { \
    __builtin_amdgcn_sched_barrier(0); \
    asm volatile("s_waitcnt lgkmcnt(0)" ::: "memory"); \
    __builtin_amdgcn_s_barrier(); \
    __builtin_amdgcn_sched_barrier(0); \
} while (0)

typedef __attribute__((ext_vector_type(8))) short bf16x8;
typedef __attribute__((ext_vector_type(4))) float f32x4;

__device__ __forceinline__ unsigned short f2b(float x) {  // fp32 -> bf16, RNE
    union { float f; unsigned u; } v; v.f = x;
    return (unsigned short)((v.u + 0x7FFF + ((v.u >> 16) & 1)) >> 16);
}
__device__ __forceinline__ unsigned pack2(float a, float b) {
    return (unsigned)f2b(a) | ((unsigned)f2b(b) << 16);
}
__device__ __forceinline__ float sigf(float x)   { return 1.f / (1.f + __expf(-x)); }
__device__ __forceinline__ float tanh_f(float x) { return 2.f / (1.f + __expf(-2.f * x)) - 1.f; }

struct Params {
    const float* input_data; const float* grids;
    const float* h0; const float* c0;
    const float* W_in;  const float* b_in;
    const float* W_obs; const float* b_obs;
    const float* b_out;
    float* outputs; float* h_all; float* c_all;
    const unsigned short* Wt; const float* biasp; const float* W_outT;
    const int* cnt; const int* lists;
};

struct SmemT {
    float hS[NODEB][132];          // owned h state, fp32 (pad 132: bank spread)
    float cS[NODEB][132];          // owned c state, fp32
    unsigned short uS[32][264];    // GEMM A: [ie(64) te(64) h(128)] bf16;
                                   // prologue: aliased as 16x98 int wslot scratch
    float gX[2][CAP][20];          // double-buffered per-winner grid(16)+x(2)
    float wObs[GG2][EMB];          // small weights, LDS-resident
    float wIn[2][EMB];
    float bIn[EMB];
    float bObs[EMB];
    float wOutT[NOUT][132];        // pad 132: breaks 5-way bank conflict
    float bOut[8];
    int wLall[TT][CAP];            // ALL winner lists (resolved in prologue)
    unsigned wMask[TT][4];         // winner-node bitmasks (zero-fill disjointness)
    int wCnt[TT];
};                                 // ~140.6 KB of 160 KB -> 1 block/CU

// Weight prep, coalesced via LDS tile transpose. 16-wave permute:
// cp = 32*wv + 16*tile + cl -> orig col = 128*(2*tile + (cl>>3)) + 8*wv + (cl&7)
__global__ __launch_bounds__(256) void prep_kernel(
    const float* __restrict__ Wih, const float* __restrict__ Whh,
    const float* __restrict__ bih, const float* __restrict__ bhh,
    const float* __restrict__ Wout,
    unsigned short* __restrict__ Wt, float* __restrict__ biasp,
    float* __restrict__ WoutT, int* __restrict__ cnt)
{
    __shared__ float tile[16][513];
    const int bx = blockIdx.x, tid = threadIdx.x;
    const int k0 = bx * 16;
    for (int i = tid; i < 16 * 512; i += 256) {
        int rr = i >> 9, cc = i & 511;
        int k = k0 + rr;
        tile[rr][cc] = (k < 128) ? Wih[k * 512 + cc] : Whh[(k - 128) * 512 + cc];
    }
    __syncthreads();
    for (int i = tid; i < 1024; i += 256) {      // 512 cp x 2 chunks of 8 k
        int cp = i >> 1, ch = i & 1;
        int wv = cp >> 5, tl = (cp >> 4) & 1, cl2 = cp & 15;
        int oc = 128 * (2 * tl + (cl2 >> 3)) + 8 * wv + (cl2 & 7);
        union { bf16x8 v; unsigned short s[8]; } u;
        #pragma unroll
        for (int e = 0; e < 8; ++e) u.s[e] = f2b(tile[8 * ch + e][oc]);
        *(bf16x8*)&Wt[cp * 256 + k0 + 8 * ch] = u.v;
    }
    if (bx == 0) {
        for (int cp = tid; cp < 512; cp += 256) {
            int wv = cp >> 5, tl = (cp >> 4) & 1, cl2 = cp & 15;
            int oc = 128 * (2 * tl + (cl2 >> 3)) + 8 * wv + (cl2 & 7);
            biasp[cp] = bih[oc] + bhh[oc];
        }
        for (int e = tid; e < NOUT * RNN; e += 256)
            WoutT[e] = Wout[(e & 127) * NOUT + (e >> 7)];
    }
    for (int i = bx * 256 + tid; i < TT * NBLK; i += 16 * 256) cnt[i] = 0;
}

// Bin each (t,k) ped to its node-owner block. Entry = k | (node_local << 14).
__global__ __launch_bounds__(256) void bin_kernel(
    const int* __restrict__ idx, int* __restrict__ cnt, int* __restrict__ lists)
{
    int e = blockIdx.x * 256 + threadIdx.x;
    if (e >= TT * KK) return;
    int t = e / KK, k = e - t * KK;
    int nd = idx[e];
    int ow = nd / NODEB, nl = nd - ow * NODEB;
    int slot = atomicAdd(&cnt[t * NBLK + ow], 1);
    if (slot < CAP) lists[((size_t)(t * NBLK + ow)) * CAP + slot] = k | (nl << 14);
}

__global__
__attribute__((amdgpu_flat_work_group_size(NTHR, NTHR), amdgpu_waves_per_eu(4, 4)))
void olstm_kernel(Params P) {
    extern __shared__ char smem_raw[];
    SmemT& S = *(SmemT*)smem_raw;
    const int tid = threadIdx.x;
    const int b   = blockIdx.x;
    const int n0  = b * NODEB;
    const int nown = (NN - n0 < NODEB) ? (NN - n0) : NODEB;
    const int w = tid >> 6, lane = tid & 63;
    const int cl = lane & 15, kq = lane >> 4;
    const int tidp = tid - 512;                   // aux-thread index (w8-15)
    const int d5 = tidp / 5, r5 = tidp - 5 * d5;  // used only when tid>=512
    const int zw = d5 >> 5, zb = d5 & 31;

    // ---- prologue: state (float4) + small weights -> LDS ----
    for (int i4 = tid * 4; i4 < nown * RNN; i4 += NTHR * 4) {
        int nl = i4 >> 7, r = i4 & 127;
        *(float4*)&S.hS[nl][r] = *(const float4*)(P.h0 + (size_t)n0 * RNN + i4);
        *(float4*)&S.cS[nl][r] = *(const float4*)(P.c0 + (size_t)n0 * RNN + i4);
    }
    for (int i = tid; i < GG2 * EMB; i += NTHR) S.wObs[i >> 6][i & 63] = P.W_obs[i];
    if (tid < 2 * EMB) S.wIn[tid >> 6][tid & 63] = P.W_in[tid];
    if (tid < EMB) { S.bIn[tid] = P.b_in[tid]; S.bObs[tid] = P.b_obs[tid]; }
    for (int i = tid; i < NOUT * RNN; i += NTHR) S.wOutT[i >> 7][i & 127] = P.W_outT[i];
    if (tid < NOUT) S.bOut[tid] = P.b_out[tid];

    // ---- B-stationary slice: 32 cols/wave -> 64 regs + 2 bias regs ----
    bf16x8 Breg[2][8];
    float bv[2];
    #pragma unroll
    for (int tl = 0; tl < 2; ++tl) {
        const unsigned short* Wb = P.Wt + ((size_t)(32 * w + 16 * tl + cl)) * 256 + kq * 8;
        #pragma unroll
        for (int ks = 0; ks < 8; ++ks) Breg[tl][ks] = *(const bf16x8*)(Wb + ks * 32);
        bv[tl] = P.biasp[32 * w + 16 * tl + cl];
    }

    // ---- winner resolution, all 20 frames (wave w: frames w, w+16);
    //      wslot scratch aliased into uS; single-wave in-order DS ----
    {
        int* wslBase = (int*)&S.uS[0][0];
        for (int t = w; t < TT; t += 16) {
            const int g = t * NBLK + b;
            int c = P.cnt[g]; c = (c > CAP) ? CAP : c;
            int* wsl = wslBase + w * NODEB;
            wsl[lane] = -1;
            if (lane + 64 < NODEB) wsl[lane + 64] = -1;
            if (lane < 4) S.wMask[t][lane] = 0u;
            int ent = 0, mk = -1, mnl = 0;
            if (lane < c) {
                ent = P.lists[(size_t)g * CAP + lane];
                mnl = ent >> 14; mk = ent & 0x3FFF;
                atomicMax(&wsl[mnl], mk);
            }
            const bool win = (lane < c) && (wsl[mnl] == mk);
            const unsigned long long ball = __ballot(win);
            const int slot = __popcll(ball & ((1ull << lane) - 1ull));
            if (win) {
                S.wLall[t][slot] = ent;
                atomicOr(&S.wMask[t][mnl >> 5], 1u << (mnl & 31));
            }
            if (lane == 0) S.wCnt[t] = __popcll(ball);
        }
    }
    BAR_LDS();

    // ---- stage gX[0] (only frame whose gather latency is exposed) ----
    if (tid >= 512) {
        const int wn0 = S.wCnt[0];
        if (tidp < 256) {
            int gm0 = tidp >> 2;
            if (gm0 < wn0) {
                int kk2 = S.wLall[0][gm0] & 0x3FFF;
                float4 gv0 = *(const float4*)(P.grids + (size_t)kk2 * GG2 + (tidp & 3) * 4);
                *(float4*)&S.gX[0][gm0][(tidp & 3) * 4] = gv0;
            }
        } else if (tidp < 320) {
            int xm = tidp - 256;
            if (xm < wn0) {
                int nl = S.wLall[0][xm] >> 14;
                float2 x2 = *(const float2*)(P.input_data + ((size_t)(n0 + nl)) * 2);
                S.gX[0][xm][16] = x2.x; S.gX[0][xm][17] = x2.y;
            }
        }
    }
    BAR_LDS();

    // ---- uS build for one 32-row super-tile (threads 0..511) ----
    auto build_tile = [&](int tf, int base, int msx) {
        const int m = tid >> 4, l = tid & 15;
        const int mrows = ((msx > 16) ? 2 : 1) << 4;
        if (m >= mrows) return;
        if (m < msx) {
            const int e = S.wLall[tf][base + m];
            const int nl2 = e >> 14;
            const float4 ha = *(const float4*)&S.hS[nl2][l * 4];
            const float4 hb = *(const float4*)&S.hS[nl2][64 + l * 4];
            *(uint2*)&S.uS[m][128 + l * 4] = make_uint2(pack2(ha.x, ha.y), pack2(ha.z, ha.w));
            *(uint2*)&S.uS[m][192 + l * 4] = make_uint2(pack2(hb.x, hb.y), pack2(hb.z, hb.w));
            const float* gx = S.gX[tf & 1][base + m];
            const float x0 = gx[16], x1 = gx[17];
            const int e0 = l * 4;
            float iv[4], tv[4];
            #pragma unroll
            for (int j = 0; j < 4; ++j) {
                iv[j] = fmaxf(fmaf(x0, S.wIn[0][e0 + j],
                              fmaf(x1, S.wIn[1][e0 + j], S.bIn[e0 + j])), 0.f);
                tv[j] = S.bObs[e0 + j];
            }
            #pragma unroll
            for (int g = 0; g < GG2; ++g) {
                const float gg = gx[g];
                #pragma unroll
                for (int j = 0; j < 4; ++j)
                    tv[j] = fmaf(gg, S.wObs[g][e0 + j], tv[j]);
            }
            *(uint2*)&S.uS[m][l * 4] =
                make_uint2(pack2(iv[0], iv[1]), pack2(iv[2], iv[3]));
            *(uint2*)&S.uS[m][64 + l * 4] =
                make_uint2(pack2(fmaxf(tv[0], 0.f), fmaxf(tv[1], 0.f)),
                           pack2(fmaxf(tv[2], 0.f), fmaxf(tv[3], 0.f)));
        } else {
            const uint2 z2 = make_uint2(0u, 0u);
            *(uint2*)&S.uS[m][l * 4]       = z2;
            *(uint2*)&S.uS[m][64 + l * 4]  = z2;
            *(uint2*)&S.uS[m][128 + l * 4] = z2;
            *(uint2*)&S.uS[m][192 + l * 4] = z2;
        }
    };

    // ---- LSTM for one 16-row m-tile: lane pair (cl, cl^8) swaps gate halves,
    //      each lane finishes 2 peds. tile0 = {i,f}, tile1 = {g,o}. ----
    const bool lolane = (cl < 8);
    const int u = 8 * w + (cl & 7);
    auto lstm_half = [&](const f32x4* ac, int mtb, int tf, int base, int msx) {
        const float r00 = __shfl_xor(ac[0][0], 8), r01 = __shfl_xor(ac[0][1], 8);
        const float r02 = __shfl_xor(ac[0][2], 8), r03 = __shfl_xor(ac[0][3], 8);
        const float r10 = __shfl_xor(ac[1][0], 8), r11 = __shfl_xor(ac[1][1], 8);
        const float r12 = __shfl_xor(ac[1][2], 8), r13 = __shfl_xor(ac[1][3], 8);
        #pragma unroll
        for (int jj = 0; jj < 2; ++jj) {
            const float a0lo = jj ? ac[0][1] : ac[0][0];
            const float a0hi = jj ? ac[0][3] : ac[0][2];
            const float a1lo = jj ? ac[1][1] : ac[1][0];
            const float a1hi = jj ? ac[1][3] : ac[1][2];
            const float r0lo = jj ? r01 : r00, r0hi = jj ? r03 : r02;
            const float r1lo = jj ? r11 : r10, r1hi = jj ? r13 : r12;
            const float iv = lolane ? a0lo : r0hi;
            const float fv = lolane ? r0lo : a0hi;
            const float gg = lolane ? a1lo : r1hi;
            const float ov = lolane ? r1lo : a1hi;
            const int m = mtb + 4 * kq + (lolane ? jj : jj + 2);
            if (m < msx) {
                const int nl2 = S.wLall[tf][base + m] >> 14;
                const float cn2 = fmaf(sigf(fv), S.cS[nl2][u], sigf(iv) * tanh_f(gg));
                const float hv = sigf(ov) * tanh_f(cn2);
                S.hS[nl2][u] = hv;   // exclusive (node, unit) per lane
                S.cS[nl2][u] = cn2;
            }
        }
    };

    // ---- one m-tile: GEMM (B from regs) then LSTM; acc working set halved
    //      vs r12 by running tiles sequentially ----
    auto gemm_lstm_tile = [&](int tf, int base, int msx, int mtb) {
        f32x4 acc[2];
        acc[0] = (f32x4){bv[0], bv[0], bv[0], bv[0]};
        acc[1] = (f32x4){bv[1], bv[1], bv[1], bv[1]};
        #pragma unroll
        for (int ks = 0; ks < 8; ++ks) {
            const bf16x8 a = *(const bf16x8*)&S.uS[mtb + cl][ks * 32 + kq * 8];
            acc[0] = __builtin_amdgcn_mfma_f32_16x16x32_bf16(a, Breg[0][ks], acc[0], 0, 0, 0);
            acc[1] = __builtin_amdgcn_mfma_f32_16x16x32_bf16(a, Breg[1][ks], acc[1], 0, 0, 0);
        }
        lstm_half(acc, mtb, tf, base, msx);
    };

    auto outproj = [&](int tf) {   // tid>=512 only; covers all wn(tf) winners
        const int wnp = S.wCnt[tf];
        if (tidp < wnp * NOUT) {
            const int nl2 = S.wLall[tf][d5] >> 14;
            const float* hp = S.hS[nl2];
            const float* wp = S.wOutT[r5];
            float a0 = S.bOut[r5], a1 = 0.f, a2 = 0.f, a3 = 0.f;
            #pragma unroll 8
            for (int rr = 0; rr < RNN; rr += 4) {
                const float4 h4 = *(const float4*)&hp[rr];
                const float4 w4 = *(const float4*)&wp[rr];
                a0 = fmaf(h4.x, w4.x, a0); a1 = fmaf(h4.y, w4.y, a1);
                a2 = fmaf(h4.z, w4.z, a2); a3 = fmaf(h4.w, w4.w, a3);
            }
            P.outputs[((size_t)tf * NN + n0 + nl2) * NOUT + r5] = (a0 + a1) + (a2 + a3);
        }
    };

    // ================= frame loop: 2 barriers/frame =================
    for (int t = 0; t < TT; ++t) {
        const int bufc = t & 1;
        const int wn = S.wCnt[t];
        const int ms0 = (wn < 32) ? wn : 32;

        float2 xv = {0.f, 0.f};
        float4 gv = {0.f, 0.f, 0.f, 0.f};
        int gm = 0, nwn = 0;

        // ---- Phase A: build(w0-7) || gather-issue(t+1) + out-proj(t-1) (w8-15)
        if (tid < 512) {
            build_tile(t, 0, ms0);
        } else {
            if (t + 1 < TT) {
                nwn = S.wCnt[t + 1];
                if (tidp < 256) {
                    gm = tidp >> 2;
                    if (gm < nwn) {
                        int kk2 = S.wLall[t + 1][gm] & 0x3FFF;
                        gv = *(const float4*)(P.grids + ((size_t)(t + 1) * KK + kk2) * GG2 + (tidp & 3) * 4);
                    }
                } else if (tidp < 320) {
                    int xm = tidp - 256;
                    if (xm < nwn) {
                        int nl = S.wLall[t + 1][xm] >> 14;
                        xv = *(const float2*)(P.input_data + ((size_t)(t + 1) * NN + n0 + nl) * 2);
                    }
                }
            }
            if (t > 0) outproj(t - 1);   // reads h(t-1); LSTM writes after BAR
        }
        BAR_LDS();

        // ---- Phase B: GEMM + LSTM (all 16 waves), m-tiles sequential ----
        gemm_lstm_tile(t, 0, ms0, 0);
        if (ms0 > 16) gemm_lstm_tile(t, 0, ms0, 16);
        for (int base = 32; base < wn; base += 32) {   // rare (P ~ 0.3%)
            BAR_LDS();
            const int msx = (wn - base < 32) ? (wn - base) : 32;
            if (tid < 512) build_tile(t, base, msx);
            BAR_LDS();
            gemm_lstm_tile(t, base, msx, 0);
            if (msx > 16) gemm_lstm_tile(t, base, msx, 16);
        }
        // aux: commit gathers (issued one phase ago) + zero-fill non-winners
        if (tid >= 512) {
            if (t + 1 < TT) {
                if (tidp < 256) {
                    if (gm < nwn) *(float4*)&S.gX[bufc ^ 1][gm][(tidp & 3) * 4] = gv;
                } else if (tidp < 320) {
                    int xm = tidp - 256;
                    if (xm < nwn) { S.gX[bufc ^ 1][xm][16] = xv.x; S.gX[bufc ^ 1][xm][17] = xv.y; }
                }
            }
            if (tidp < nown * NOUT && !((S.wMask[t][zw] >> zb) & 1u))
                P.outputs[(size_t)t * NN * NOUT + n0 * NOUT + tidp] = 0.f;
        }
        BAR_LDS();
    }

    // ---- epilogue: out-proj(19) (w8-15) || state writeback (w0-7) ----
    if (tid >= 512) {
        outproj(TT - 1);
    } else {
        for (int i4 = tid * 4; i4 < nown * RNN; i4 += 512 * 4) {
            int nl = i4 >> 7, r = i4 & 127;
            *(float4*)(P.h_all + (size_t)n0 * RNN + i4) = *(const float4*)&S.hS[nl][r];
            *(float4*)(P.c_all + (size_t)n0 * RNN + i4) = *(const float4*)&S.cS[nl][r];
        }
    }
}

extern "C" void kernel_launch(void* const* d_in, const int* in_sizes, int n_in,
                              void* d_out, int out_size, void* d_ws, size_t ws_size,
                              hipStream_t stream) {
    Params P;
    P.input_data = (const float*)d_in[0];
    P.grids      = (const float*)d_in[1];
    P.h0         = (const float*)d_in[2];
    P.c0         = (const float*)d_in[3];
    const int* active_idx = (const int*)d_in[4];
    P.W_in  = (const float*)d_in[5];
    P.b_in  = (const float*)d_in[6];
    P.W_obs = (const float*)d_in[7];
    P.b_obs = (const float*)d_in[8];
    const float* W_ih = (const float*)d_in[9];
    const float* b_ih = (const float*)d_in[10];
    const float* W_hh = (const float*)d_in[11];
    const float* b_hh = (const float*)d_in[12];
    const float* W_out = (const float*)d_in[13];
    P.b_out = (const float*)d_in[14];

    // d_out: outputs[T*N*5] | h_fin[N*128] | c_fin[N*128]
    P.outputs = (float*)d_out;
    P.h_all   = P.outputs + (size_t)TT * NN * NOUT;
    P.c_all   = P.h_all + (size_t)NN * RNN;

    // d_ws: Wt | biasp | W_outT | cnt | lists
    char* ws = (char*)d_ws;
    unsigned short* Wt = (unsigned short*)ws;  ws += (size_t)512 * 256 * sizeof(unsigned short);
    float* biasp = (float*)ws;                 ws += 512 * sizeof(float);
    float* WoT   = (float*)ws;                 ws += (size_t)NOUT * RNN * sizeof(float);
    int* cnt     = (int*)ws;                   ws += (size_t)TT * NBLK * sizeof(int);
    int* lists   = (int*)ws;
    P.Wt = Wt; P.biasp = biasp; P.W_outT = WoT; P.cnt = cnt; P.lists = lists;

    // 3 dispatches (winner resolution folded into olstm prologue)
    prep_kernel<<<16, 256, 0, stream>>>(W_ih, W_hh, b_ih, b_hh, W_out, Wt, biasp, WoT, cnt);
    bin_kernel<<<(TT * KK + 255) / 256, 256, 0, stream>>>(active_idx, cnt, lists);

    // ~140.6 KB dynamic LDS (gfx950: 160 KB/CU) -> 1 block/CU, 16 waves (4/SIMD)
    int smem = (int)sizeof(SmemT);
    hipFuncSetAttribute((const void*)olstm_kernel,
                        hipFuncAttributeMaxDynamicSharedMemorySize, smem);
    olstm_kernel<<<NBLK, NTHR, smem, stream>>>(P);
}

// Round 7
// 436.320 us; speedup vs baseline: 1.7707x; 1.6238x over previous
//
#include <hip/hip_runtime.h>

// OLSTM: T=20 frames, N=50000 nodes, K=10000 active peds/frame
// RNN=128, EMB=64, IN=2, OUT=5, G2=16
//
// Round 14: consolidation on the proven 8-wave base (r10: 297.9us, VGPR 120,
// no spill). The 16-wave line (r12/r13) is dead: allocator pins 1024-thr
// blocks at 64 VGPR and spills Breg (520 MB scratch). Ported the validated
// pieces back:
//  - winner resolution in olstm prologue (r12-proven): no winner_kernel,
//    no per-frame list prefetch; all 20 lists LDS-resident (wLall, +5.4 KB).
//  - 2 barriers/frame (was 3): A{issue gathers(t+1), build(t), outproj(t-1),
//    zero-fill(t)} BAR B{GEMM+LSTM, commit gX} BAR. outproj(t-1) only READS
//    hS (so does build; LSTM writes only in B); its stores are disjoint from
//    zero-fill via wMask (r11-proven).
//  - plain __syncthreads (r11: lgkm-only barriers neutral), r11 coalesced prep.
// GEMM/LSTM/build/outproj bodies byte-identical to r10. 3 dispatches.
#define TT    20
#define NN    50000
#define KK    10000
#define RNN   128
#define EMB   64
#define GG2   16
#define NOUT  5
#define NODEB 98
#define NBLK  ((NN + NODEB - 1) / NODEB)   // 511 blocks
#define CAP   64                           // peds per (frame, block); E[n]=19.6
#define NTHR  512                          // 8 waves

// gather-issue thread ranges (coexist sequentially with build in phase A)
#define G_BASE 192                         // grid gather: 192..447 (4*CAP)
#define X_BASE 448                         // x gather:    448..511 (CAP)

typedef __attribute__((ext_vector_type(8))) short bf16x8;
typedef __attribute__((ext_vector_type(4))) float f32x4;

__device__ __forceinline__ unsigned short f2b(float x) {  // fp32 -> bf16, RNE
    union { float f; unsigned u; } v; v.f = x;
    return (unsigned short)((v.u + 0x7FFF + ((v.u >> 16) & 1)) >> 16);
}
__device__ __forceinline__ unsigned pack2(float a, float b) {
    return (unsigned)f2b(a) | ((unsigned)f2b(b) << 16);
}
__device__ __forceinline__ float sigf(float x)   { return 1.f / (1.f + __expf(-x)); }
__device__ __forceinline__ float tanh_f(float x) { return 2.f / (1.f + __expf(-2.f * x)) - 1.f; }

struct Params {
    const float* input_data; const float* grids;
    const float* h0; const float* c0;
    const float* W_in;  const float* b_in;
    const float* W_obs; const float* b_obs;
    const float* b_out;
    float* outputs; float* h_all; float* c_all;
    const unsigned short* Wt; const float* biasp; const float* W_outT;
    const int* cnt; const int* lists;
};

struct SmemT {
    float hS[NODEB][132];          // owned h state, fp32 (pad 132: bank spread)
    float cS[NODEB][132];          // owned c state, fp32
    unsigned short uS[32][264];    // GEMM A: [ie(64) te(64) h(128)] bf16;
                                   // prologue: aliased as 8x98 int wslot scratch
    float gX[2][CAP][20];          // double-buffered per-winner grid(16)+x(2)
    float wObs[GG2][EMB];          // small weights, LDS-resident
    float wIn[2][EMB];
    float bIn[EMB];
    float bObs[EMB];
    float biasp[512];
    float wOutT[NOUT][132];        // pad 132: breaks 5-way bank conflict
    float bOut[8];
    int wLall[TT][CAP];            // ALL winner lists (resolved in prologue)
    unsigned wMask[TT][4];         // winner-node bitmasks (zero-fill disjointness)
    int wCnt[TT];
};                                 // ~142.6 KB of 160 KB -> 1 block/CU

// Weight prep, coalesced via LDS tile transpose (r11). 8-wave permute:
// cp = 64*wq + 16*gate + cl -> orig col = 128*gate + 16*wq + cl.
// Block 0 also builds biasp + W_outT; cnt zeroing spread over all blocks.
__global__ __launch_bounds__(256) void prep_kernel(
    const float* __restrict__ Wih, const float* __restrict__ Whh,
    const float* __restrict__ bih, const float* __restrict__ bhh,
    const float* __restrict__ Wout,
    unsigned short* __restrict__ Wt, float* __restrict__ biasp,
    float* __restrict__ WoutT, int* __restrict__ cnt)
{
    __shared__ float tile[16][513];
    const int bx = blockIdx.x, tid = threadIdx.x;
    const int k0 = bx * 16;
    for (int i = tid; i < 16 * 512; i += 256) {
        int rr = i >> 9, cc = i & 511;
        int k = k0 + rr;
        tile[rr][cc] = (k < 128) ? Wih[k * 512 + cc] : Whh[(k - 128) * 512 + cc];
    }
    __syncthreads();
    for (int i = tid; i < 1024; i += 256) {      // 512 cp x 2 chunks of 8 k
        int cp = i >> 1, ch = i & 1;
        int wq = cp >> 6, rem = cp & 63, gate = rem >> 4, cl2 = rem & 15;
        int oc = 128 * gate + 16 * wq + cl2;
        union { bf16x8 v; unsigned short s[8]; } u;
        #pragma unroll
        for (int e = 0; e < 8; ++e) u.s[e] = f2b(tile[8 * ch + e][oc]);
        *(bf16x8*)&Wt[cp * 256 + k0 + 8 * ch] = u.v;
    }
    if (bx == 0) {
        for (int cp = tid; cp < 512; cp += 256) {
            int wq = cp >> 6, rem = cp & 63, gate = rem >> 4, cl2 = rem & 15;
            int oc = 128 * gate + 16 * wq + cl2;
            biasp[cp] = bih[oc] + bhh[oc];
        }
        for (int e = tid; e < NOUT * RNN; e += 256)
            WoutT[e] = Wout[(e & 127) * NOUT + (e >> 7)];
    }
    for (int i = bx * 256 + tid; i < TT * NBLK; i += 16 * 256) cnt[i] = 0;
}

// Bin each (t,k) ped to its node-owner block. Entry = k | (node_local << 14).
__global__ __launch_bounds__(256) void bin_kernel(
    const int* __restrict__ idx, int* __restrict__ cnt, int* __restrict__ lists)
{
    int e = blockIdx.x * 256 + threadIdx.x;
    if (e >= TT * KK) return;
    int t = e / KK, k = e - t * KK;
    int nd = idx[e];
    int ow = nd / NODEB, nl = nd - ow * NODEB;
    int slot = atomicAdd(&cnt[t * NBLK + ow], 1);
    if (slot < CAP) lists[((size_t)(t * NBLK + ow)) * CAP + slot] = k | (nl << 14);
}

__global__ __launch_bounds__(NTHR, 2) void olstm_kernel(Params P) {
    extern __shared__ char smem_raw[];
    SmemT& S = *(SmemT*)smem_raw;
    const int tid = threadIdx.x;
    const int b   = blockIdx.x;
    const int n0  = b * NODEB;
    const int nown = (NN - n0 < NODEB) ? (NN - n0) : NODEB;
    const int w = tid >> 6, lane = tid & 63;
    const int cl = lane & 15, kq = lane >> 4;
    const int d5 = tid / 5, r5 = tid - 5 * d5;   // outproj (tid<320) & zero-fill (tid<490)
    const int zw = d5 >> 5, zb = d5 & 31;        // zero-fill mask word/bit

    // ---- prologue: state (float4) + small weights -> LDS ----
    for (int i4 = tid * 4; i4 < nown * RNN; i4 += NTHR * 4) {
        int nl = i4 >> 7, r = i4 & 127;
        *(float4*)&S.hS[nl][r] = *(const float4*)(P.h0 + (size_t)n0 * RNN + i4);
        *(float4*)&S.cS[nl][r] = *(const float4*)(P.c0 + (size_t)n0 * RNN + i4);
    }
    for (int i = tid; i < GG2 * EMB; i += NTHR) S.wObs[i >> 6][i & 63] = P.W_obs[i];
    if (tid < 2 * EMB) S.wIn[tid >> 6][tid & 63] = P.W_in[tid];
    if (tid < EMB) { S.bIn[tid] = P.b_in[tid]; S.bObs[tid] = P.b_obs[tid]; }
    S.biasp[tid] = P.biasp[tid];
    for (int i = tid; i < NOUT * RNN; i += NTHR) S.wOutT[i >> 7][i & 127] = P.W_outT[i];
    if (tid < NOUT) S.bOut[tid] = P.b_out[tid];

    // ---- B-stationary: whole Wt tile for this lane, held all kernel (AGPRs) ----
    bf16x8 Breg[4][8];
    {
        const unsigned short* Wb = P.Wt + ((size_t)(64 * w + cl)) * 256 + kq * 8;
        #pragma unroll
        for (int gate = 0; gate < 4; ++gate)
            #pragma unroll
            for (int ks = 0; ks < 8; ++ks)
                Breg[gate][ks] = *(const bf16x8*)(Wb + (size_t)gate * 16 * 256 + ks * 32);
    }

    // ---- winner resolution, all 20 frames (wave w: t = w, w+8, w+16);
    //      wslot scratch aliased into uS; single-wave in-order DS ----
    {
        int* wsl = (int*)&S.uS[0][0] + w * NODEB;
        for (int t = w; t < TT; t += 8) {
            const int g = t * NBLK + b;
            int c = P.cnt[g]; c = (c > CAP) ? CAP : c;
            wsl[lane] = -1;
            if (lane + 64 < NODEB) wsl[lane + 64] = -1;
            if (lane < 4) S.wMask[t][lane] = 0u;
            int ent = 0, mk = -1, mnl = 0;
            if (lane < c) {
                ent = P.lists[(size_t)g * CAP + lane];
                mnl = ent >> 14; mk = ent & 0x3FFF;
                atomicMax(&wsl[mnl], mk);
            }
            const bool win = (lane < c) && (wsl[mnl] == mk);
            const unsigned long long ball = __ballot(win);
            const int slot = __popcll(ball & ((1ull << lane) - 1ull));
            if (win) {
                S.wLall[t][slot] = ent;
                atomicOr(&S.wMask[t][mnl >> 5], 1u << (mnl & 31));
            }
            if (lane == 0) S.wCnt[t] = __popcll(ball);
        }
    }
    __syncthreads();

    // ---- stage gX[0] (only frame whose gather latency is exposed) ----
    {
        const int wn0 = S.wCnt[0];
        if (tid >= X_BASE) {
            int xm = tid - X_BASE;
            if (xm < wn0) {
                int nl = S.wLall[0][xm] >> 14;
                float2 x2 = *(const float2*)(P.input_data + ((size_t)(n0 + nl)) * 2);
                S.gX[0][xm][16] = x2.x; S.gX[0][xm][17] = x2.y;
            }
        } else if (tid >= G_BASE) {
            int gm0 = (tid - G_BASE) >> 2;
            if (gm0 < wn0) {
                int kk2 = S.wLall[0][gm0] & 0x3FFF;
                float4 gv0 = *(const float4*)(P.grids + (size_t)kk2 * GG2 + (tid & 3) * 4);
                *(float4*)&S.gX[0][gm0][(tid & 3) * 4] = gv0;
            }
        }
    }
    __syncthreads();

    // ---- uS build for one 32-row super-tile (r10 body, wLall) ----
    auto build_tile = [&](int tf, int base, int msx) {
        const int m = tid >> 4, l = tid & 15;
        const int mrows = ((msx > 16) ? 2 : 1) << 4;
        if (m >= mrows) return;
        if (m < msx) {
            const int e = S.wLall[tf][base + m];
            const int nl2 = e >> 14;
            const float4 ha = *(const float4*)&S.hS[nl2][l * 4];
            const float4 hb = *(const float4*)&S.hS[nl2][64 + l * 4];
            *(uint2*)&S.uS[m][128 + l * 4] = make_uint2(pack2(ha.x, ha.y), pack2(ha.z, ha.w));
            *(uint2*)&S.uS[m][192 + l * 4] = make_uint2(pack2(hb.x, hb.y), pack2(hb.z, hb.w));
            const float* gx = S.gX[tf & 1][base + m];
            const float x0 = gx[16], x1 = gx[17];
            const int e0 = l * 4;
            float iv[4], tv[4];
            #pragma unroll
            for (int j = 0; j < 4; ++j) {
                iv[j] = fmaxf(fmaf(x0, S.wIn[0][e0 + j],
                              fmaf(x1, S.wIn[1][e0 + j], S.bIn[e0 + j])), 0.f);
                tv[j] = S.bObs[e0 + j];
            }
            #pragma unroll
            for (int g = 0; g < GG2; ++g) {
                const float gg = gx[g];
                #pragma unroll
                for (int j = 0; j < 4; ++j)
                    tv[j] = fmaf(gg, S.wObs[g][e0 + j], tv[j]);
            }
            *(uint2*)&S.uS[m][l * 4] =
                make_uint2(pack2(iv[0], iv[1]), pack2(iv[2], iv[3]));
            *(uint2*)&S.uS[m][64 + l * 4] =
                make_uint2(pack2(fmaxf(tv[0], 0.f), fmaxf(tv[1], 0.f)),
                           pack2(fmaxf(tv[2], 0.f), fmaxf(tv[3], 0.f)));
        } else {
            const uint2 z2 = make_uint2(0u, 0u);
            *(uint2*)&S.uS[m][l * 4]       = z2;
            *(uint2*)&S.uS[m][64 + l * 4]  = z2;
            *(uint2*)&S.uS[m][128 + l * 4] = z2;
            *(uint2*)&S.uS[m][192 + l * 4] = z2;
        }
    };

    // ---- gates GEMM (B from registers) + lane-local LSTM (r10 body) ----
    auto gemm_lstm = [&](int tf, int base, int msx, int nmtx) {
        const int r = 16 * w + cl;
        f32x4 acc0[4];
        #pragma unroll
        for (int gate = 0; gate < 4; ++gate) {
            const float bvv = S.biasp[64 * w + 16 * gate + cl];
            acc0[gate] = (f32x4){bvv, bvv, bvv, bvv};
        }
        if (nmtx == 2) {
            f32x4 acc1[4];
            #pragma unroll
            for (int gate = 0; gate < 4; ++gate) acc1[gate] = acc0[gate];
            #pragma unroll
            for (int ks = 0; ks < 8; ++ks) {
                const int kk = ks * 32;
                const bf16x8 a0 = *(const bf16x8*)&S.uS[cl][kk + kq * 8];
                const bf16x8 a1 = *(const bf16x8*)&S.uS[16 + cl][kk + kq * 8];
                #pragma unroll
                for (int gate = 0; gate < 4; ++gate) {
                    acc0[gate] = __builtin_amdgcn_mfma_f32_16x16x32_bf16(a0, Breg[gate][ks], acc0[gate], 0, 0, 0);
                    acc1[gate] = __builtin_amdgcn_mfma_f32_16x16x32_bf16(a1, Breg[gate][ks], acc1[gate], 0, 0, 0);
                }
            }
            #pragma unroll
            for (int reg = 0; reg < 4; ++reg) {
                const int m = 4 * kq + reg;
                if (m < msx) {
                    const int nl2 = S.wLall[tf][base + m] >> 14;
                    const float cn2 = fmaf(sigf(acc0[1][reg]), S.cS[nl2][r],
                                           sigf(acc0[0][reg]) * tanh_f(acc0[2][reg]));
                    const float hv = sigf(acc0[3][reg]) * tanh_f(cn2);
                    S.hS[nl2][r] = hv;   // exclusive (node, r) per lane
                    S.cS[nl2][r] = cn2;
                }
            }
            #pragma unroll
            for (int reg = 0; reg < 4; ++reg) {
                const int m = 16 + 4 * kq + reg;
                if (m < msx) {
                    const int nl2 = S.wLall[tf][base + m] >> 14;
                    const float cn2 = fmaf(sigf(acc1[1][reg]), S.cS[nl2][r],
                                           sigf(acc1[0][reg]) * tanh_f(acc1[2][reg]));
                    const float hv = sigf(acc1[3][reg]) * tanh_f(cn2);
                    S.hS[nl2][r] = hv;
                    S.cS[nl2][r] = cn2;
                }
            }
        } else {
            #pragma unroll
            for (int ks = 0; ks < 8; ++ks) {
                const int kk = ks * 32;
                const bf16x8 a0 = *(const bf16x8*)&S.uS[cl][kk + kq * 8];
                #pragma unroll
                for (int gate = 0; gate < 4; ++gate)
                    acc0[gate] = __builtin_amdgcn_mfma_f32_16x16x32_bf16(a0, Breg[gate][ks], acc0[gate], 0, 0, 0);
            }
            #pragma unroll
            for (int reg = 0; reg < 4; ++reg) {
                const int m = 4 * kq + reg;
                if (m < msx) {
                    const int nl2 = S.wLall[tf][base + m] >> 14;
                    const float cn2 = fmaf(sigf(acc0[1][reg]), S.cS[nl2][r],
                                           sigf(acc0[0][reg]) * tanh_f(acc0[2][reg]));
                    const float hv = sigf(acc0[3][reg]) * tanh_f(cn2);
                    S.hS[nl2][r] = hv;
                    S.cS[nl2][r] = cn2;
                }
            }
        }
    };

    // ---- out projection for frame tf (tid<320 covers all <=64 winners) ----
    auto outproj = [&](int tf) {
        if (tid >= 320) return;
        if (d5 >= S.wCnt[tf]) return;
        const int nl2 = S.wLall[tf][d5] >> 14;
        const float* hp = S.hS[nl2];
        const float* wp = S.wOutT[r5];
        float a0 = S.bOut[r5], a1 = 0.f, a2 = 0.f, a3 = 0.f;
        #pragma unroll 8
        for (int rr = 0; rr < RNN; rr += 4) {
            const float4 h4 = *(const float4*)&hp[rr];
            const float4 w4 = *(const float4*)&wp[rr];
            a0 = fmaf(h4.x, w4.x, a0); a1 = fmaf(h4.y, w4.y, a1);
            a2 = fmaf(h4.z, w4.z, a2); a3 = fmaf(h4.w, w4.w, a3);
        }
        P.outputs[((size_t)tf * NN + n0 + nl2) * NOUT + r5] = (a0 + a1) + (a2 + a3);
    };

    // ================= frame loop: 2 barriers/frame =================
    for (int t = 0; t < TT; ++t) {
        const int bufc = t & 1;
        const int wn = S.wCnt[t];
        const int ms0 = (wn < 32) ? wn : 32;
        const int nmt0 = (ms0 > 16) ? 2 : 1;

        // ---- Phase A ----
        // A1: issue gathers for t+1 (into regs; commit in B)
        float2 xv = {0.f, 0.f};
        float4 gv = {0.f, 0.f, 0.f, 0.f};
        int gm = 0, nwn = 0;
        if (t + 1 < TT) {
            nwn = S.wCnt[t + 1];
            if (tid >= X_BASE) {
                int xm = tid - X_BASE;
                if (xm < nwn) {
                    int nl = S.wLall[t + 1][xm] >> 14;
                    xv = *(const float2*)(P.input_data + ((size_t)(t + 1) * NN + n0 + nl) * 2);
                }
            } else if (tid >= G_BASE) {
                gm = (tid - G_BASE) >> 2;
                if (gm < nwn) {
                    int kk2 = S.wLall[t + 1][gm] & 0x3FFF;
                    gv = *(const float4*)(P.grids + ((size_t)(t + 1) * KK + kk2) * GG2 + (tid & 3) * 4);
                }
            }
        }
        // A2: build uS(t) (reads hS, gX[bufc])
        build_tile(t, 0, ms0);
        // A3: out-proj(t-1) (reads hS only -- LSTM(t) writes after BAR1)
        if (t > 0) outproj(t - 1);
        // A4: zero-fill non-winner outputs(t) (disjoint from all winner stores)
        if (tid < nown * NOUT && !((S.wMask[t][zw] >> zb) & 1u))
            P.outputs[(size_t)t * NN * NOUT + n0 * NOUT + tid] = 0.f;
        __syncthreads();   // BAR1

        // ---- Phase B: GEMM + LSTM ----
        gemm_lstm(t, 0, ms0, nmt0);
        for (int base = 32; base < wn; base += 32) {   // rare (P ~ 0.3%)
            __syncthreads();
            const int msx = (wn - base < 32) ? (wn - base) : 32;
            build_tile(t, base, msx);
            __syncthreads();
            gemm_lstm(t, base, msx, (msx > 16) ? 2 : 1);
        }
        // commit prefetched gX[t+1]
        if (t + 1 < TT) {
            if (tid >= X_BASE) {
                int xm = tid - X_BASE;
                if (xm < nwn) { S.gX[bufc ^ 1][xm][16] = xv.x; S.gX[bufc ^ 1][xm][17] = xv.y; }
            } else if (tid >= G_BASE) {
                if (gm < nwn) *(float4*)&S.gX[bufc ^ 1][gm][(tid & 3) * 4] = gv;
            }
        }
        __syncthreads();   // BAR2
    }

    // ---- epilogue: out-proj(19), then state writeback (float4, coalesced) ----
    outproj(TT - 1);
    for (int i4 = tid * 4; i4 < nown * RNN; i4 += NTHR * 4) {
        int nl = i4 >> 7, r = i4 & 127;
        *(float4*)(P.h_all + (size_t)n0 * RNN + i4) = *(const float4*)&S.hS[nl][r];
        *(float4*)(P.c_all + (size_t)n0 * RNN + i4) = *(const float4*)&S.cS[nl][r];
    }
}

extern "C" void kernel_launch(void* const* d_in, const int* in_sizes, int n_in,
                              void* d_out, int out_size, void* d_ws, size_t ws_size,
                              hipStream_t stream) {
    Params P;
    P.input_data = (const float*)d_in[0];
    P.grids      = (const float*)d_in[1];
    P.h0         = (const float*)d_in[2];
    P.c0         = (const float*)d_in[3];
    const int* active_idx = (const int*)d_in[4];
    P.W_in  = (const float*)d_in[5];
    P.b_in  = (const float*)d_in[6];
    P.W_obs = (const float*)d_in[7];
    P.b_obs = (const float*)d_in[8];
    const float* W_ih = (const float*)d_in[9];
    const float* b_ih = (const float*)d_in[10];
    const float* W_hh = (const float*)d_in[11];
    const float* b_hh = (const float*)d_in[12];
    const float* W_out = (const float*)d_in[13];
    P.b_out = (const float*)d_in[14];

    // d_out: outputs[T*N*5] | h_fin[N*128] | c_fin[N*128]
    P.outputs = (float*)d_out;
    P.h_all   = P.outputs + (size_t)TT * NN * NOUT;
    P.c_all   = P.h_all + (size_t)NN * RNN;

    // d_ws: Wt | biasp | W_outT | cnt | lists
    char* ws = (char*)d_ws;
    unsigned short* Wt = (unsigned short*)ws;  ws += (size_t)512 * 256 * sizeof(unsigned short);
    float* biasp = (float*)ws;                 ws += 512 * sizeof(float);
    float* WoT   = (float*)ws;                 ws += (size_t)NOUT * RNN * sizeof(float);
    int* cnt     = (int*)ws;                   ws += (size_t)TT * NBLK * sizeof(int);
    int* lists   = (int*)ws;
    P.Wt = Wt; P.biasp = biasp; P.W_outT = WoT; P.cnt = cnt; P.lists = lists;

    // 3 dispatches (winner resolution folded into olstm prologue)
    prep_kernel<<<16, 256, 0, stream>>>(W_ih, W_hh, b_ih, b_hh, W_out, Wt, biasp, WoT, cnt);
    bin_kernel<<<(TT * KK + 255) / 256, 256, 0, stream>>>(active_idx, cnt, lists);

    // ~142.6 KB dynamic LDS (gfx950: 160 KB/CU) -> 1 block/CU, 8 waves
    int smem = (int)sizeof(SmemT);
    hipFuncSetAttribute((const void*)olstm_kernel,
                        hipFuncAttributeMaxDynamicSharedMemorySize, smem);
    olstm_kernel<<<NBLK, NTHR, smem, stream>>>(P);
}